// Round 9
// baseline (394.320 us; speedup 1.0000x reference)
//
#include <hip/hip_runtime.h>
#include <cstdint>
#include <cstddef>

#define NN 50000
#define NE 800000
#define HID 256
#define TDIM 128

#define CHB 16384          // bins per histogram chunk (64 KB LDS)
#define NSL 16             // edge slices
#define SLE (NE / NSL)     // 50000 edges per slice

typedef short bf16x8 __attribute__((ext_vector_type(8)));
typedef float f32x4 __attribute__((ext_vector_type(4)));

#define GLOAD_LDS16(g, l)                                                        \
  __builtin_amdgcn_global_load_lds(                                              \
      (const __attribute__((address_space(1))) unsigned int*)(g),                \
      (__attribute__((address_space(3))) unsigned int*)(l), 16, 0, 0)

__device__ inline unsigned short f2bf(float f) {
  uint32_t u = __builtin_bit_cast(uint32_t, f);
  uint32_t r = u + 0x7FFFu + ((u >> 16) & 1u);
  return (unsigned short)(r >> 16);
}
__device__ inline float bf2f(unsigned short s) {
  uint32_t u = ((uint32_t)s) << 16;
  return __builtin_bit_cast(float, u);
}
__device__ inline float fast_sig(float x) {
  return __builtin_amdgcn_rcpf(1.0f + __expf(-x));
}
__device__ inline float fast_tanh(float x) {
  float xc = fminf(fmaxf(x, -10.0f), 10.0f);
  float e = __expf(2.0f * xc);
  return 1.0f - 2.0f * __builtin_amdgcn_rcpf(e + 1.0f);
}

// ---------------- hidden -> bf16 plane ----------------
__global__ __launch_bounds__(256) void cvt_hidden(const float* __restrict__ x,
                                                  short* __restrict__ xb) {
  int i = blockIdx.x * 256 + threadIdx.x;   // one float4 per thread
  if (i < NN * HID / 4) {
    float4 v = ((const float4*)x)[i];
    unsigned int lo = (unsigned int)f2bf(v.x) | ((unsigned int)f2bf(v.y) << 16);
    unsigned int hi = (unsigned int)f2bf(v.z) | ((unsigned int)f2bf(v.w) << 16);
    ((uint2*)xb)[i] = make_uint2(lo, hi);
  }
}

// ---------------- histogram phase A: LDS-privatized partial counts ----------------
__global__ __launch_bounds__(1024) void hist_part(const int* __restrict__ src,
                                                  const int* __restrict__ dst,
                                                  int* __restrict__ P) {
  __shared__ int h[CHB];
  const int b = blockIdx.x;          // 8 * NSL blocks
  const int c = b & 7, s = b >> 3;
  for (int j = threadIdx.x; j < CHB; j += 1024) h[j] = 0;
  __syncthreads();
  const int* arr = (c < 4) ? src : dst;
  const int base = (c & 3) * CHB;
  const int e0 = s * SLE;
  for (int i = threadIdx.x; i < SLE; i += 1024) {
    int v = arr[e0 + i] - base;
    if ((unsigned)v < CHB) atomicAdd(&h[v], 1);
  }
  __syncthreads();
  int* Pc = P + (size_t)(c * NSL + s) * CHB;
  for (int j = threadIdx.x; j < CHB; j += 1024) Pc[j] = h[j];
}

// ---------------- phase B: reduce -> norms; in-place exclusive scan of in-partials ----------------
__global__ __launch_bounds__(256) void hist_reduce(int* __restrict__ P,
                                                   float* __restrict__ onorm,
                                                   float* __restrict__ inorm,
                                                   int* __restrict__ icnt) {
  int n = blockIdx.x * 256 + threadIdx.x;
  if (n >= 4 * CHB) return;
  const int c = n >> 14, j = n & (CHB - 1);
  int* Po = P + (size_t)(c * NSL) * CHB + j;
  int od = 0;
#pragma unroll
  for (int s = 0; s < NSL; ++s) od += Po[(size_t)s * CHB];
  int* Pi = P + (size_t)((4 + c) * NSL) * CHB + j;
  int run = 0;
#pragma unroll
  for (int s = 0; s < NSL; ++s) { int t = Pi[(size_t)s * CHB]; Pi[(size_t)s * CHB] = run; run += t; }
  if (n < NN) {
    onorm[n] = 1.0f / sqrtf(fmaxf((float)od, 1.0f));
    inorm[n] = 1.0f / sqrtf(fmaxf((float)run, 1.0f));
    icnt[n] = run;
  }
}

// ---------------- CSR row scan (int counts) ----------------
__global__ __launch_bounds__(1024) void scan_rows(const int* __restrict__ icnt,
                                                  int* __restrict__ rowstart) {
  __shared__ int wsum[16];
  __shared__ int carry_s;
  const int tid = threadIdx.x, lane = tid & 63, w = tid >> 6;
  if (tid == 0) { carry_s = 0; rowstart[0] = 0; }
  __syncthreads();
  for (int base = 0; base < NN; base += 8192) {
    int i0 = base + tid * 8;
    int c[8];
    int v = 0;
#pragma unroll
    for (int j = 0; j < 8; ++j) {
      int i = i0 + j;
      c[j] = (i < NN) ? icnt[i] : 0;
      v += c[j];
    }
    int inc = v;
#pragma unroll
    for (int off = 1; off < 64; off <<= 1) {
      int t = __shfl_up(inc, off, 64);
      if (lane >= off) inc += t;
    }
    if (lane == 63) wsum[w] = inc;
    __syncthreads();
    int woff = 0;
    for (int k = 0; k < w; ++k) woff += wsum[k];
    int carry = carry_s;
    int run = carry + woff + inc - v;
#pragma unroll
    for (int j = 0; j < 8; ++j) {
      int i = i0 + j;
      if (i < NN) rowstart[i + 1] = run + c[j];
      run += c[j];
    }
    __syncthreads();
    if (tid == 1023) carry_s = carry + woff + inc;
    __syncthreads();
  }
}

// ---------------- CSR fill via LDS cursors (no global atomics) ----------------
__global__ __launch_bounds__(1024) void fill_csr2(const int* __restrict__ src,
                                                  const int* __restrict__ dst,
                                                  const float* __restrict__ onorm,
                                                  const int* __restrict__ rowstart,
                                                  const int* __restrict__ P,
                                                  int* __restrict__ col,
                                                  float* __restrict__ ewt) {
  __shared__ int cur[CHB];
  const int b = blockIdx.x;          // 4 * NSL blocks
  const int c = b & 3, s = b >> 2;
  const int base = c * CHB;
  const int* Pi = P + (size_t)((4 + c) * NSL + s) * CHB;
  for (int j = threadIdx.x; j < CHB; j += 1024) {
    int n = base + j;
    cur[j] = (n < NN ? rowstart[n] : 0) + Pi[j];
  }
  __syncthreads();
  const int e0 = s * SLE;
  for (int i = threadIdx.x; i < SLE; i += 1024) {
    int d = dst[e0 + i] - base;
    if ((unsigned)d < CHB) {
      int sv = src[e0 + i];
      int pos = atomicAdd(&cur[d], 1);   // LDS atomic: fast
      col[pos] = sv;
      ewt[pos] = onorm[sv];
    }
  }
}

// ---------------- gather aggregation (bf16 in -> bf16 out), 8-edge unroll ----------------
__global__ __launch_bounds__(256) void gather_agg(const short* __restrict__ xB,
                                                  const int* __restrict__ rowstart,
                                                  const int* __restrict__ col,
                                                  const float* __restrict__ ewt,
                                                  const float* __restrict__ inorm,
                                                  short* __restrict__ aggB) {
  const int wid = blockIdx.x * 4 + (threadIdx.x >> 6);
  const int lane = threadIdx.x & 63;
  if (wid >= NN) return;
  const int e1 = rowstart[wid + 1];
  int e = rowstart[wid];
  const int fo = lane * 4;
  float a[4] = {0.f, 0.f, 0.f, 0.f};
  for (; e + 8 <= e1; e += 8) {
    int ss[8]; float ww[8]; uint2 uu[8];
#pragma unroll
    for (int q = 0; q < 8; ++q) { ss[q] = col[e + q]; ww[q] = ewt[e + q]; }
#pragma unroll
    for (int q = 0; q < 8; ++q) uu[q] = *(const uint2*)(xB + (size_t)ss[q] * HID + fo);
#pragma unroll
    for (int q = 0; q < 8; ++q) {
      a[0] = fmaf(bf2f((unsigned short)(uu[q].x & 0xFFFF)), ww[q], a[0]);
      a[1] = fmaf(bf2f((unsigned short)(uu[q].x >> 16)),    ww[q], a[1]);
      a[2] = fmaf(bf2f((unsigned short)(uu[q].y & 0xFFFF)), ww[q], a[2]);
      a[3] = fmaf(bf2f((unsigned short)(uu[q].y >> 16)),    ww[q], a[3]);
    }
  }
  for (; e + 2 <= e1; e += 2) {
    int s0 = col[e], s1 = col[e + 1];
    float w0 = ewt[e], w1 = ewt[e + 1];
    uint2 u0 = *(const uint2*)(xB + (size_t)s0 * HID + fo);
    uint2 u1 = *(const uint2*)(xB + (size_t)s1 * HID + fo);
    a[0] = fmaf(bf2f((unsigned short)(u0.x & 0xFFFF)), w0, a[0]);
    a[1] = fmaf(bf2f((unsigned short)(u0.x >> 16)),    w0, a[1]);
    a[2] = fmaf(bf2f((unsigned short)(u0.y & 0xFFFF)), w0, a[2]);
    a[3] = fmaf(bf2f((unsigned short)(u0.y >> 16)),    w0, a[3]);
    a[0] = fmaf(bf2f((unsigned short)(u1.x & 0xFFFF)), w1, a[0]);
    a[1] = fmaf(bf2f((unsigned short)(u1.x >> 16)),    w1, a[1]);
    a[2] = fmaf(bf2f((unsigned short)(u1.y & 0xFFFF)), w1, a[2]);
    a[3] = fmaf(bf2f((unsigned short)(u1.y >> 16)),    w1, a[3]);
  }
  if (e < e1) {
    int s0 = col[e];
    float w0 = ewt[e];
    uint2 u0 = *(const uint2*)(xB + (size_t)s0 * HID + fo);
    a[0] = fmaf(bf2f((unsigned short)(u0.x & 0xFFFF)), w0, a[0]);
    a[1] = fmaf(bf2f((unsigned short)(u0.x >> 16)),    w0, a[1]);
    a[2] = fmaf(bf2f((unsigned short)(u0.y & 0xFFFF)), w0, a[2]);
    a[3] = fmaf(bf2f((unsigned short)(u0.y >> 16)),    w0, a[3]);
  }
  const float wi = inorm[wid];
  unsigned int lo = (unsigned int)f2bf(a[0] * wi) | ((unsigned int)f2bf(a[1] * wi) << 16);
  unsigned int hi = (unsigned int)f2bf(a[2] * wi) | ((unsigned int)f2bf(a[3] * wi) << 16);
  *(uint2*)(aggB + (size_t)wid * HID + fo) = make_uint2(lo, hi);
}

// ---------------- fused weight prep ----------------
__global__ __launch_bounds__(256) void wprep(const float* __restrict__ W1,
                                             const float* __restrict__ W2,
                                             const float* __restrict__ W_ih,
                                             const float* __restrict__ W_hh,
                                             const float* __restrict__ t,
                                             const float* __restrict__ tw,
                                             const float* __restrict__ tb,
                                             const float* __restrict__ b_ih,
                                             const float* __restrict__ b_hh,
                                             short* __restrict__ W1B,
                                             short* __restrict__ W2B,
                                             short* __restrict__ WgB,
                                             float* __restrict__ cst) {
  const int b = blockIdx.x;
  const int k = threadIdx.x;
  if (b < 256) {
    W1B[b * 256 + k] = (short)f2bf(W1[k * 256 + b]);
    W2B[b * 256 + k] = (short)f2bf(W2[k * 256 + b]);
  } else if (b < 512) {
    int u = b - 256;
    int base = (u >> 4) * 64 + (u & 15);
    float v0 = W_ih[(size_t)u * 384 + k] + W_hh[(size_t)u * 256 + k];
    float v1 = W_ih[(size_t)(256 + u) * 384 + k] + W_hh[(size_t)(256 + u) * 256 + k];
    float v2 = W_ih[(size_t)(512 + u) * 384 + k];
    float v3 = W_hh[(size_t)(512 + u) * 256 + k];
    WgB[(size_t)(base + 0)  * 256 + k] = (short)f2bf(v0);
    WgB[(size_t)(base + 16) * 256 + k] = (short)f2bf(v1);
    WgB[(size_t)(base + 32) * 256 + k] = (short)f2bf(v2);
    WgB[(size_t)(base + 48) * 256 + k] = (short)f2bf(v3);
  } else {
    __shared__ float te[TDIM];
    int u = k;
    if (u < TDIM) te[u] = cosf(t[0] * tw[u] + tb[u]);
    __syncthreads();
    float cr = b_ih[u] + b_hh[u];
    float cz = b_ih[256 + u] + b_hh[256 + u];
    float ci = b_ih[512 + u];
    for (int kk = 0; kk < TDIM; ++kk) {
      float tk = te[kk];
      cr = fmaf(tk, W_ih[(size_t)u * 384 + 256 + kk], cr);
      cz = fmaf(tk, W_ih[(size_t)(256 + u) * 384 + 256 + kk], cz);
      ci = fmaf(tk, W_ih[(size_t)(512 + u) * 384 + 256 + kk], ci);
    }
    cst[u] = cr;
    cst[256 + u] = cz;
    cst[512 + u] = ci;
    cst[768 + u] = b_hh[512 + u];
  }
}

// ---------------- MFMA GEMM v6: 3-buffer ring, counted vmcnt (T3+T4), raw barriers ----------------
// Block tile 128x128, 4 waves (2x2), wave tile 64x64, BK=32, 8 k-steps.
// Iter t: s_waitcnt vmcnt(4) [stage t landed, stage t+1 in flight] -> s_barrier ->
//         issue stage t+2 into buf[(t+2)%3] -> ds_read buf[t%3] + 16 MFMA.
// Never drains vmcnt(0) in steady state; loads get 2 k-steps of latency budget.
template <int CT, bool GRUE, bool DUAL>
__global__ __launch_bounds__(256, 3) void gemm_v6(const short* __restrict__ A,
                                                  const short* __restrict__ B,
                                                  const float* __restrict__ bias,
                                                  const float* __restrict__ cst,
                                                  const short* __restrict__ hHp,
                                                  const short* __restrict__ hLp,
                                                  short* __restrict__ outH,
                                                  short* __restrict__ outL,
                                                  float* __restrict__ outF) {
  __shared__ __align__(16) short As[3][128 * 32];
  __shared__ __align__(16) short Bs[3][128 * 32];

  const int nwg = gridDim.x;
  const int xcd = blockIdx.x & 7, jj = blockIdx.x >> 3;
  const int q = nwg >> 3, r = nwg & 7;
  const int lidx = (xcd < r ? xcd * (q + 1) : r * (q + 1) + (xcd - r) * q) + jj;
  const int strip = lidx / CT;
  const int ct = lidx % CT;
  const int row0 = strip * 128;
  const int col0 = ct * 128;

  const int tid = threadIdx.x;
  const int l = tid & 63, wv = tid >> 6;
  const int wm = wv >> 1, wn = wv & 1;
  const int fr = l & 15, fg = l >> 4;

  // per-thread staging geometry (2 A rows + 2 B rows, 16B each)
  int arow[2], asw[2], brow[2];
#pragma unroll
  for (int i = 0; i < 2; ++i) {
    int id = tid + i * 256;
    int row = id >> 2, sp = id & 3;
    int s = (sp - (row >> 1)) & 3;
    int gr = row0 + row;
    arow[i] = (gr < NN ? gr : NN - 1);
    asw[i] = s;
    brow[i] = col0 + row;
  }

  f32x4 acc[4][4];
#pragma unroll
  for (int i = 0; i < 4; ++i)
#pragma unroll
    for (int j = 0; j < 4; ++j) acc[i][j] = (f32x4)(0.0f);

  // prologue: stage k-steps 0 and 1 (8 vm-ops/thread outstanding)
#pragma unroll
  for (int i = 0; i < 2; ++i) {
    int id = tid + i * 256;
    GLOAD_LDS16(A + (size_t)arow[i] * HID + 0 + asw[i] * 8, &As[0][id * 8]);
    GLOAD_LDS16(B + (size_t)brow[i] * HID + 0 + asw[i] * 8, &Bs[0][id * 8]);
  }
#pragma unroll
  for (int i = 0; i < 2; ++i) {
    int id = tid + i * 256;
    GLOAD_LDS16(A + (size_t)arow[i] * HID + 32 + asw[i] * 8, &As[1][id * 8]);
    GLOAD_LDS16(B + (size_t)brow[i] * HID + 32 + asw[i] * 8, &Bs[1][id * 8]);
  }

#pragma unroll
  for (int t = 0; t < 8; ++t) {
    // wait for stage t only (stage t+1 stays in flight); drain fully at the end
    if (t < 7) {
      asm volatile("s_waitcnt vmcnt(4)" ::: "memory");
    } else {
      asm volatile("s_waitcnt vmcnt(0)" ::: "memory");
    }
    __builtin_amdgcn_sched_barrier(0);
    __builtin_amdgcn_s_barrier();
    asm volatile("" ::: "memory");

    if (t < 6) {
      const int kn = (t + 2) * 32;
      const int nb = (t + 2) % 3;
#pragma unroll
      for (int i = 0; i < 2; ++i) {
        int id = tid + i * 256;
        GLOAD_LDS16(A + (size_t)arow[i] * HID + kn + asw[i] * 8, &As[nb][id * 8]);
        GLOAD_LDS16(B + (size_t)brow[i] * HID + kn + asw[i] * 8, &Bs[nb][id * 8]);
      }
    }

    const int buf = t % 3;
    bf16x8 bh[4];
#pragma unroll
    for (int nf = 0; nf < 4; ++nf) {
      int rr = wn * 64 + nf * 16 + fr;
      bh[nf] = *(const bf16x8*)(&Bs[buf][rr * 32 + (((fg + (rr >> 1)) & 3) << 3)]);
    }
#pragma unroll
    for (int mf = 0; mf < 4; ++mf) {
      int rr = wm * 64 + mf * 16 + fr;
      bf16x8 ah = *(const bf16x8*)(&As[buf][rr * 32 + (((fg + (rr >> 1)) & 3) << 3)]);
#pragma unroll
      for (int nf = 0; nf < 4; ++nf)
        acc[mf][nf] = __builtin_amdgcn_mfma_f32_16x16x32_bf16(ah, bh[nf], acc[mf][nf], 0, 0, 0);
    }
  }

  if constexpr (!GRUE) {
#pragma unroll
    for (int mf = 0; mf < 4; ++mf) {
      int rbase = row0 + wm * 64 + mf * 16 + fg * 4;
#pragma unroll
      for (int nf = 0; nf < 4; ++nf) {
        int c = col0 + wn * 64 + nf * 16 + fr;
        float bs = bias[c];
#pragma unroll
        for (int j = 0; j < 4; ++j) {
          int row = rbase + j;
          if (row < NN) {
            float v = fmaxf(acc[mf][nf][j] + bs, 0.0f);
            unsigned short hv_ = f2bf(v);
            size_t off = (size_t)row * HID + c;
            outH[off] = (short)hv_;
            if constexpr (DUAL) outL[off] = (short)f2bf(v - bf2f(hv_));
          }
        }
      }
    }
  } else {
    const int u = (ct * 2 + wn) * 16 + fr;
    const float cr = cst[u], cz = cst[256 + u], ci = cst[512 + u], chn = cst[768 + u];
#pragma unroll
    for (int mf = 0; mf < 4; ++mf) {
      int rbase = row0 + wm * 64 + mf * 16 + fg * 4;
#pragma unroll
      for (int j = 0; j < 4; ++j) {
        int row = rbase + j;
        if (row < NN) {
          float dr = acc[mf][0][j] + cr;
          float dz = acc[mf][1][j] + cz;
          float dn = acc[mf][2][j] + ci;
          float dh = acc[mf][3][j] + chn;
          float rg = fast_sig(dr);
          float zg = fast_sig(dz);
          float ng = fast_tanh(dn + rg * dh);
          size_t off = (size_t)row * HID + u;
          float hv = bf2f((unsigned short)hHp[off]) + bf2f((unsigned short)hLp[off]);
          outF[off] = (1.0f - zg) * ng + zg * hv;
        }
      }
    }
  }
}

extern "C" void kernel_launch(void* const* d_in, const int* in_sizes, int n_in,
                              void* d_out, int out_size, void* d_ws, size_t ws_size,
                              hipStream_t stream) {
  const float* hidden = (const float*)d_in[0];
  const float* t      = (const float*)d_in[1];
  const int*   src    = (const int*)d_in[2];
  const int*   dst    = (const int*)d_in[3];
  const float* W1     = (const float*)d_in[4];
  const float* b1     = (const float*)d_in[5];
  const float* W2     = (const float*)d_in[6];
  const float* b2     = (const float*)d_in[7];
  const float* time_w = (const float*)d_in[8];
  const float* time_b = (const float*)d_in[9];
  const float* W_ih   = (const float*)d_in[10];
  const float* W_hh   = (const float*)d_in[11];
  const float* b_ih   = (const float*)d_in[12];
  const float* b_hh   = (const float*)d_in[13];
  float* out = (float*)d_out;

  char* p = (char*)d_ws;
  float* onorm = (float*)p;      p += 50048 * 4;
  float* inorm = (float*)p;      p += 50048 * 4;
  float* cst   = (float*)p;      p += 1024 * 4;
  int* rowstart = (int*)p;       p += 50052 * 4;
  int* icnt     = (int*)p;       p += 50048 * 4;
  int* ecol     = (int*)p;       p += 800000 * 4;
  float* ewt    = (float*)p;     p += 800000 * 4;
  const size_t NFE = (size_t)NN * HID;
  short* Xb   = (short*)p;       p += NFE * 2;
  short* aggB = (short*)p;       p += NFE * 2;
  short* h1B  = (short*)p;       p += NFE * 2;
  short* h2H  = (short*)p;       p += NFE * 2;
  short* h2L  = (short*)p;       p += NFE * 2;
  short* W1B  = (short*)p;       p += 65536 * 2;
  short* W2B  = (short*)p;       p += 65536 * 2;
  short* WgB  = (short*)p;       p += 262144 * 2;
  // partial-histogram workspace aliases h2H (8*NSL*CHB ints = 8.4 MB < 25.6 MB;
  // h2H is only written by layer-2 GEMM, after fill_csr2 has consumed P)
  int* P = (int*)h2H;

  // independent prep first
  cvt_hidden<<<(NN * HID / 4 + 255) / 256, 256, 0, stream>>>(hidden, Xb);
  wprep<<<513, 256, 0, stream>>>(W1, W2, W_ih, W_hh, t, time_w, time_b, b_ih, b_hh,
                                 W1B, W2B, WgB, cst);

  // graph prep: privatized histograms -> norms/prefix -> row scan -> LDS-cursor fill
  hist_part<<<8 * NSL, 1024, 0, stream>>>(src, dst, P);
  hist_reduce<<<(4 * CHB + 255) / 256, 256, 0, stream>>>(P, onorm, inorm, icnt);
  scan_rows<<<1, 1024, 0, stream>>>(icnt, rowstart);
  fill_csr2<<<4 * NSL, 1024, 0, stream>>>(src, dst, onorm, rowstart, P, ecol, ewt);

  const int gather_blocks = (NN + 3) / 4;
  const int strips = (NN + 127) / 128;   // 391

  // layer 1
  gather_agg<<<gather_blocks, 256, 0, stream>>>(Xb, rowstart, ecol, ewt, inorm, aggB);
  gemm_v6<2, false, false><<<strips * 2, 256, 0, stream>>>(aggB, W1B, b1, nullptr, nullptr, nullptr, h1B, nullptr, nullptr);

  // layer 2 (writes hi+lo planes; lo only needed for GRU carry)
  gather_agg<<<gather_blocks, 256, 0, stream>>>(h1B, rowstart, ecol, ewt, inorm, aggB);
  gemm_v6<2, false, true><<<strips * 2, 256, 0, stream>>>(aggB, W2B, b2, nullptr, nullptr, nullptr, h2H, h2L, nullptr);

  // GRU: 8 col-tiles per strip, XCD-chunked so A strip stays in one L2
  gemm_v6<8, true, false><<<strips * 8, 256, 0, stream>>>(h2H, WgB, nullptr, cst, h2H, h2L, nullptr, nullptr, out);
}